// Round 5
// baseline (152.055 us; speedup 1.0000x reference)
//
#include <hip/hip_runtime.h>
#include <hip/hip_bf16.h>

// RewardCLIP loss:
//   diff[i] = dot(input_embs[i] - neg_input_embs[i], image_embs[i])
//   loss = -mean(log_sigmoid(diff * alpha))
//
// Memory-bound: 3 x 65536 x 1024 x 4B = 768 MiB read; R0 structure runs at
// 5.76 TB/s effective (91% of the 6.29 TB/s copy ceiling).
// R4: exact R0 loop body (compiler-scheduled, 20 VGPR) with reduced overhead:
// 512 blocks x 1024 threads (same wave count, same per-wave access order),
// 4x fewer block epilogues, 512 partials, single-wave shuffle-only finalize.
// Lessons: R2 agent-scope acq/rel atomics thrash L2 (-2.3x); R3 hand-batched
// loads + memset/atomic tail cost more than the finalize dispatch saves.

#define DIMS 1024
#define BLOCKS 512
#define THREADS 1024
#define WAVES_PER_BLOCK (THREADS / 64)

__global__ __launch_bounds__(THREADS) void rewardclip_main(
    const float* __restrict__ a,      // input_embs
    const float* __restrict__ b,      // neg_input_embs
    const float* __restrict__ c,      // image_embs
    const int* __restrict__ alpha_p,  // scalar (python int)
    int rows,
    float* __restrict__ partials) {
  const int tid  = threadIdx.x;
  const int lane = tid & 63;
  const int wave = tid >> 6;
  const int gwave  = blockIdx.x * WAVES_PER_BLOCK + wave;
  const int nwaves = gridDim.x * WAVES_PER_BLOCK;

  const float alpha = (float)(*alpha_p);

  float acc = 0.0f;  // lane-0-valid accumulator of log_sigmoid values

  for (int row = gwave; row < rows; row += nwaves) {
    const float4* __restrict__ pa = (const float4*)(a + (size_t)row * DIMS);
    const float4* __restrict__ pb = (const float4*)(b + (size_t)row * DIMS);
    const float4* __restrict__ pc = (const float4*)(c + (size_t)row * DIMS);

    float d = 0.0f;
#pragma unroll
    for (int j = 0; j < DIMS / (64 * 4); ++j) {   // 4 iterations
      const int idx = j * 64 + lane;              // float4 index; lanes contiguous
      const float4 va = pa[idx];
      const float4 vb = pb[idx];
      const float4 vc = pc[idx];
      d += (va.x - vb.x) * vc.x;
      d += (va.y - vb.y) * vc.y;
      d += (va.z - vb.z) * vc.z;
      d += (va.w - vb.w) * vc.w;
    }

    // 64-lane shuffle reduction
#pragma unroll
    for (int off = 32; off > 0; off >>= 1) d += __shfl_down(d, off, 64);

    if (lane == 0) {
      const float x = d * alpha;
      const float ls = fminf(x, 0.0f) - log1pf(__expf(-fabsf(x)));
      acc += ls;
    }
  }

  __shared__ float s[WAVES_PER_BLOCK];
  if (lane == 0) s[wave] = acc;
  __syncthreads();
  if (tid == 0) {
    float t = 0.0f;
#pragma unroll
    for (int w = 0; w < WAVES_PER_BLOCK; ++w) t += s[w];
    partials[blockIdx.x] = t;  // fully overwritten every launch: deterministic
  }
}

__global__ __launch_bounds__(64) void rewardclip_finalize(
    const float* __restrict__ partials, int nparts, int rows,
    float* __restrict__ out) {
  const int lane = threadIdx.x;  // single wave: no LDS, no syncthreads
  float s = 0.0f;
  for (int i = lane; i < nparts; i += 64) s += partials[i];
#pragma unroll
  for (int off = 32; off > 0; off >>= 1) s += __shfl_down(s, off, 64);
  if (lane == 0) out[0] = -s / (float)rows;
}

extern "C" void kernel_launch(void* const* d_in, const int* in_sizes, int n_in,
                              void* d_out, int out_size, void* d_ws, size_t ws_size,
                              hipStream_t stream) {
  const float* a = (const float*)d_in[0];       // input_embs
  const float* b = (const float*)d_in[1];       // neg_input_embs
  const float* c = (const float*)d_in[2];       // image_embs
  const int* alpha_p = (const int*)d_in[3];     // python int scalar

  const int rows = in_sizes[0] / DIMS;          // 65536
  float* partials = (float*)d_ws;               // BLOCKS floats
  float* out = (float*)d_out;

  rewardclip_main<<<BLOCKS, THREADS, 0, stream>>>(a, b, c, alpha_p, rows, partials);
  rewardclip_finalize<<<1, 64, 0, stream>>>(partials, BLOCKS, rows, out);
}

// Round 6
// 147.619 us; speedup vs baseline: 1.0300x; 1.0300x over previous
//
#include <hip/hip_runtime.h>
#include <hip/hip_bf16.h>

// RewardCLIP loss:
//   diff[i] = dot(input_embs[i] - neg_input_embs[i], image_embs[i])
//   loss = -mean(log_sigmoid(diff * alpha))
//
// Memory-bound: 3 x 65536 x 1024 x 4B = 768 MiB mandatory read.
// R5 = revert to R0's exact main kernel (best measured: 139.9 us,
// 5.96 TB/s effective ~ 95% of achievable read-path ceiling) + R4's
// single-wave finalize.
// Failed-experiment ledger:
//   R1 hand-batched 12-load MLP: null (compiler re-interleaves; not latency-bound)
//   R2 agent-scope acq/rel last-block-done: -2.3x (L2 invalidate storm)
//   R3 single kernel + atomicAdd + memset: +9 us (VGPR 36, occupancy drop)
//   R4 512x1024 blocks: +12 us (block-granularity / tail imbalance)

#define DIMS 1024
#define BLOCKS 2048
#define THREADS 256
#define WAVES_PER_BLOCK (THREADS / 64)

__global__ __launch_bounds__(THREADS) void rewardclip_main(
    const float* __restrict__ a,      // input_embs
    const float* __restrict__ b,      // neg_input_embs
    const float* __restrict__ c,      // image_embs
    const int* __restrict__ alpha_p,  // scalar (python int)
    int rows,
    float* __restrict__ partials) {
  const int tid  = threadIdx.x;
  const int lane = tid & 63;
  const int wave = tid >> 6;
  const int gwave  = blockIdx.x * WAVES_PER_BLOCK + wave;
  const int nwaves = gridDim.x * WAVES_PER_BLOCK;

  const float alpha = (float)(*alpha_p);

  float acc = 0.0f;  // lane-0-valid accumulator of log_sigmoid values

  for (int row = gwave; row < rows; row += nwaves) {
    const float4* __restrict__ pa = (const float4*)(a + (size_t)row * DIMS);
    const float4* __restrict__ pb = (const float4*)(b + (size_t)row * DIMS);
    const float4* __restrict__ pc = (const float4*)(c + (size_t)row * DIMS);

    float d = 0.0f;
#pragma unroll
    for (int j = 0; j < DIMS / (64 * 4); ++j) {   // 4 iterations
      const int idx = j * 64 + lane;              // float4 index; lanes contiguous
      const float4 va = pa[idx];
      const float4 vb = pb[idx];
      const float4 vc = pc[idx];
      d += (va.x - vb.x) * vc.x;
      d += (va.y - vb.y) * vc.y;
      d += (va.z - vb.z) * vc.z;
      d += (va.w - vb.w) * vc.w;
    }

    // 64-lane shuffle reduction
#pragma unroll
    for (int off = 32; off > 0; off >>= 1) d += __shfl_down(d, off, 64);

    if (lane == 0) {
      const float x = d * alpha;
      const float ls = fminf(x, 0.0f) - log1pf(__expf(-fabsf(x)));
      acc += ls;
    }
  }

  __shared__ float s[WAVES_PER_BLOCK];
  if (lane == 0) s[wave] = acc;
  __syncthreads();
  if (tid == 0) {
    float t = 0.0f;
#pragma unroll
    for (int w = 0; w < WAVES_PER_BLOCK; ++w) t += s[w];
    partials[blockIdx.x] = t;  // fully overwritten every launch: deterministic
  }
}

__global__ __launch_bounds__(64) void rewardclip_finalize(
    const float* __restrict__ partials, int nparts, int rows,
    float* __restrict__ out) {
  const int lane = threadIdx.x;  // single wave: no LDS, no syncthreads
  float s = 0.0f;
  for (int i = lane; i < nparts; i += 64) s += partials[i];
#pragma unroll
  for (int off = 32; off > 0; off >>= 1) s += __shfl_down(s, off, 64);
  if (lane == 0) out[0] = -s / (float)rows;
}

extern "C" void kernel_launch(void* const* d_in, const int* in_sizes, int n_in,
                              void* d_out, int out_size, void* d_ws, size_t ws_size,
                              hipStream_t stream) {
  const float* a = (const float*)d_in[0];       // input_embs
  const float* b = (const float*)d_in[1];       // neg_input_embs
  const float* c = (const float*)d_in[2];       // image_embs
  const int* alpha_p = (const int*)d_in[3];     // python int scalar

  const int rows = in_sizes[0] / DIMS;          // 65536
  float* partials = (float*)d_ws;               // BLOCKS floats
  float* out = (float*)d_out;

  rewardclip_main<<<BLOCKS, THREADS, 0, stream>>>(a, b, c, alpha_p, rows, partials);
  rewardclip_finalize<<<1, 64, 0, stream>>>(partials, BLOCKS, rows, out);
}

// Round 7
// 139.488 us; speedup vs baseline: 1.0901x; 1.0583x over previous
//
#include <hip/hip_runtime.h>
#include <hip/hip_bf16.h>

// RewardCLIP loss:
//   pos[i] = dot(input_embs[i], image_embs[i])
//   neg[i] = dot(neg_input_embs[i], image_embs[i])
//   loss = -mean(log_sigmoid((pos - neg) * alpha))
// Fused: diff[i] = dot(input_embs[i] - neg_input_embs[i], image_embs[i])
//
// Memory-bound: 3 x 65536 x 1024 x 4B = 768 MiB mandatory read.
// R6 = exact R0 restore (best measured: 139.9 us = 5.75 TB/s effective,
// ~91% of the 6.29 TB/s copy ceiling; main loop alone ~6.0 TB/s).
// Failed-experiment ledger:
//   R1 hand-batched 12-load MLP: null (compiler re-interleaves; not latency-bound)
//   R2 agent-scope acq/rel last-block-done: -2.3x (L2 invalidate storm)
//   R3 single kernel + atomicAdd + memset: +9 us (VGPR 36, occupancy drop)
//   R4 512x1024 blocks: +12 us (block-granularity / tail imbalance)
//   R5 64-thread finalize: +8 us vs R0 (serial tail chain / session noise)

#define DIMS 1024
#define BLOCKS 2048
#define THREADS 256
#define WAVES_PER_BLOCK (THREADS / 64)

__global__ __launch_bounds__(THREADS) void rewardclip_main(
    const float* __restrict__ a,      // input_embs
    const float* __restrict__ b,      // neg_input_embs
    const float* __restrict__ c,      // image_embs
    const int* __restrict__ alpha_p,  // scalar (python int)
    int rows,
    float* __restrict__ partials) {
  const int tid  = threadIdx.x;
  const int lane = tid & 63;
  const int wave = tid >> 6;
  const int gwave  = blockIdx.x * WAVES_PER_BLOCK + wave;
  const int nwaves = gridDim.x * WAVES_PER_BLOCK;

  const float alpha = (float)(*alpha_p);

  float acc = 0.0f;  // per-(wave,lane) accumulator of log_sigmoid values (valid in lane 0)

  for (int row = gwave; row < rows; row += nwaves) {
    const float4* __restrict__ pa = (const float4*)(a + (size_t)row * DIMS);
    const float4* __restrict__ pb = (const float4*)(b + (size_t)row * DIMS);
    const float4* __restrict__ pc = (const float4*)(c + (size_t)row * DIMS);

    float d = 0.0f;
#pragma unroll
    for (int j = 0; j < DIMS / (64 * 4); ++j) {   // 4 iterations
      const int idx = j * 64 + lane;              // float4 index; lanes contiguous
      const float4 va = pa[idx];
      const float4 vb = pb[idx];
      const float4 vc = pc[idx];
      d += (va.x - vb.x) * vc.x;
      d += (va.y - vb.y) * vc.y;
      d += (va.z - vb.z) * vc.z;
      d += (va.w - vb.w) * vc.w;
    }

    // 64-lane shuffle reduction
#pragma unroll
    for (int off = 32; off > 0; off >>= 1) d += __shfl_down(d, off, 64);

    if (lane == 0) {
      const float x = d * alpha;
      // numerically stable log_sigmoid
      const float ls = fminf(x, 0.0f) - log1pf(__expf(-fabsf(x)));
      acc += ls;
    }
  }

  __shared__ float s[WAVES_PER_BLOCK];
  if (lane == 0) s[wave] = acc;
  __syncthreads();
  if (tid == 0) {
    float t = 0.0f;
#pragma unroll
    for (int w = 0; w < WAVES_PER_BLOCK; ++w) t += s[w];
    partials[blockIdx.x] = t;  // fully overwritten every launch: deterministic
  }
}

__global__ __launch_bounds__(THREADS) void rewardclip_finalize(
    const float* __restrict__ partials, int nparts, int rows,
    float* __restrict__ out) {
  const int tid  = threadIdx.x;
  const int lane = tid & 63;
  const int wave = tid >> 6;

  float s = 0.0f;
  for (int i = tid; i < nparts; i += THREADS) s += partials[i];

#pragma unroll
  for (int off = 32; off > 0; off >>= 1) s += __shfl_down(s, off, 64);

  __shared__ float ws[WAVES_PER_BLOCK];
  if (lane == 0) ws[wave] = s;
  __syncthreads();
  if (tid == 0) {
    float t = 0.0f;
#pragma unroll
    for (int w = 0; w < WAVES_PER_BLOCK; ++w) t += ws[w];
    out[0] = -t / (float)rows;
  }
}

extern "C" void kernel_launch(void* const* d_in, const int* in_sizes, int n_in,
                              void* d_out, int out_size, void* d_ws, size_t ws_size,
                              hipStream_t stream) {
  const float* a = (const float*)d_in[0];       // input_embs
  const float* b = (const float*)d_in[1];       // neg_input_embs
  const float* c = (const float*)d_in[2];       // image_embs
  const int* alpha_p = (const int*)d_in[3];     // python int scalar

  const int rows = in_sizes[0] / DIMS;          // 65536
  float* partials = (float*)d_ws;               // BLOCKS floats
  float* out = (float*)d_out;

  rewardclip_main<<<BLOCKS, THREADS, 0, stream>>>(a, b, c, alpha_p, rows, partials);
  rewardclip_finalize<<<1, THREADS, 0, stream>>>(partials, BLOCKS, rows, out);
}